// Round 13
// baseline (224.882 us; speedup 1.0000x reference)
//
#include <hip/hip_runtime.h>

typedef __attribute__((ext_vector_type(8))) short bf16x8;
typedef __attribute__((ext_vector_type(4))) float f32x4;
typedef __attribute__((ext_vector_type(4))) int i32x4;
typedef __attribute__((ext_vector_type(4))) float float4v;

#define MFMA16(a, b, c) __builtin_amdgcn_mfma_f32_16x16x32_bf16((a), (b), (c), 0, 0, 0)

__device__ __forceinline__ unsigned short f2bf(float f) {
    unsigned u = __builtin_bit_cast(unsigned, f);
    u += 0x7fffu + ((u >> 16) & 1u);
    return (unsigned short)(u >> 16);
}
__device__ __forceinline__ float bf2f(unsigned short s) {
    unsigned u = ((unsigned)s) << 16;
    return __builtin_bit_cast(float, u);
}
__device__ __forceinline__ int pkbf(float a, float b) {
    return (int)f2bf(a) | ((int)f2bf(b) << 16);
}

// LDS map: see round-12 comments (identical).
#define KOFF 131072
#define LOFF 147456

// INSTRUMENTATION ROUND: identical to round 12 except the P4 key-tile loop
// executes 16x (reps 0..14 discarded via *0.0f reset that keeps the dep chain
// live so the compiler cannot DCE the reps). P4 cost = (total-101.6)/15.
#define P4_REPS 16

__global__ __launch_bounds__(512, 2) void battn_kernel(
    const float* __restrict__ x,
    const float* __restrict__ Wq, const float* __restrict__ bq,
    const float* __restrict__ Wk, const float* __restrict__ bk,
    const float* __restrict__ Wv, const float* __restrict__ bv,
    const float* __restrict__ gamma, float* __restrict__ out)
{
    __shared__ __attribute__((aligned(128))) char smem[147968];
    const int tid = threadIdx.x;
    const int bid = blockIdx.x;
    const int p  = ((bid & 7) << 3) | (bid >> 5);   // 64 blocks, 4 wgs/p per XCD
    const int qq = (bid >> 3) & 3;                  // query quarter
    const int ib = p >> 3, jb = p & 7;
    const int vbase = ib * 8 * 4096 + jb * 8 * 64 + ib * 8;
    const int lane = tid & 63, wv = tid >> 6;
    const int g = lane >> 4, c15 = lane & 15;

    // phase 0: stage FULL x block -> blk^T bf16 (swizzled), batched 8-deep.
    #pragma unroll
    for (int b = 0; b < 4; ++b) {
        float4v t[8];
        #pragma unroll
        for (int j = 0; j < 8; ++j) {
            int ch = (b * 8 + j) * 512 + tid;
            int c = ch >> 7;
            int m = (ch & 127) * 4;
            int vox = ((m >> 6) << 12) + (((m >> 3) & 7) << 6) + (m & 7);
            t[j] = *(const float4v*)(x + c * 262144 + vbase + vox);
        }
        #pragma unroll
        for (int j = 0; j < 8; ++j) {
            int ch = (b * 8 + j) * 512 + tid;
            int c = ch >> 7;
            int m = (ch & 127) * 4;
            char* bp = smem + ((m * 256 + 2 * c) ^ (((m >> 2) & 7) << 4));
            *(unsigned short*)(bp)       = f2bf(t[j][0]);
            *(unsigned short*)(bp + 256) = f2bf(t[j][1]);
            *(unsigned short*)(bp + 512) = f2bf(t[j][2]);
            *(unsigned short*)(bp + 768) = f2bf(t[j][3]);
        }
    }

    // weight fragments (fp32 global -> bf16 regs), vectorized float4 loads
    bf16x8 wqf[4], wkf[4], wvf[4];
    #pragma unroll
    for (int ks = 0; ks < 4; ++ks) {
        const float4v* sq = (const float4v*)(Wq + c15 * 128 + ks * 32 + g * 8);
        const float4v* sk = (const float4v*)(Wk + c15 * 128 + ks * 32 + g * 8);
        const float4v* sv = (const float4v*)(Wv + (wv * 16 + c15) * 128 + ks * 32 + g * 8);
        float4v q0 = sq[0], q1 = sq[1];
        float4v k0 = sk[0], k1 = sk[1];
        float4v v0 = sv[0], v1 = sv[1];
        #pragma unroll
        for (int e = 0; e < 4; ++e) {
            wqf[ks][e] = (short)f2bf(q0[e]); wqf[ks][4 + e] = (short)f2bf(q1[e]);
            wkf[ks][e] = (short)f2bf(k0[e]); wkf[ks][4 + e] = (short)f2bf(k1[e]);
            wvf[ks][e] = (short)f2bf(v0[e]); wvf[ks][4 + e] = (short)f2bf(v1[e]);
        }
    }
    const float bqv = bq[c15], bkv = bk[c15];
    const f32x4 zacc = {0.f, 0.f, 0.f, 0.f};
    const bf16x8 zfrag = (bf16x8)(short)0;

    __syncthreads();   // B1: blkT staged

    // P1: qhat for this wave's 16 queries (tile qq*128 + wv*16), wave-local
    {
        f32x4 acc = zacc;
        int mrow = qq * 128 + wv * 16 + c15;
        int sw = ((mrow >> 2) & 7) << 4;
        #pragma unroll
        for (int ks = 0; ks < 4; ++ks) {
            bf16x8 af = *(const bf16x8*)(smem + ((mrow * 256 + ks * 64 + g * 16) ^ sw));
            acc = MFMA16(af, wqf[ks], acc);
        }
        #pragma unroll
        for (int r = 0; r < 4; ++r)
            *(unsigned short*)(smem + KOFF + wv * 2048 + (g * 4 + r) * 32 + 2 * c15) = f2bf(acc[r] + bqv);
    }
    bf16x8 qf = zfrag;
    if (g < 2) qf = *(const bf16x8*)(smem + KOFF + wv * 2048 + c15 * 32 + g * 16);

    // P2: Khat[mk][d] for this wave's 64 keys (overwrites own scratch slice)
    #pragma unroll
    for (int qi = 0; qi < 4; ++qi) {
        f32x4 acc = zacc;
        int mrow = wv * 64 + qi * 16 + c15;
        int sw = ((mrow >> 2) & 7) << 4;
        #pragma unroll
        for (int ks = 0; ks < 4; ++ks) {
            bf16x8 af = *(const bf16x8*)(smem + ((mrow * 256 + ks * 64 + g * 16) ^ sw));
            acc = MFMA16(af, wkf[ks], acc);
        }
        #pragma unroll
        for (int r = 0; r < 4; ++r) {
            int mk = wv * 64 + qi * 16 + g * 4 + r;
            *(unsigned short*)(smem + KOFF + mk * 32 + 2 * c15) = f2bf(acc[r] + bkv);
        }
    }

    // P3: Vhat in 4 chunks of 128 keys, in-place over consumed blkT rows
    for (int ck = 0; ck < 4; ++ck) {
        f32x4 vacc[8];
        #pragma unroll
        for (int mt = 0; mt < 8; ++mt) {
            vacc[mt] = zacc;
            int mrow = ck * 128 + mt * 16 + c15;
            int sw = ((mrow >> 2) & 7) << 4;
            #pragma unroll
            for (int ks = 0; ks < 4; ++ks) {
                bf16x8 bf = *(const bf16x8*)(smem + ((mrow * 256 + ks * 64 + g * 16) ^ sw));
                vacc[mt] = MFMA16(wvf[ks], bf, vacc[mt]);
            }
        }
        __syncthreads();
        #pragma unroll
        for (int mt = 0; mt < 8; ++mt) {
            #pragma unroll
            for (int r = 0; r < 4; ++r) {
                int c_out = wv * 16 + g * 4 + r;
                int mkl = mt * 16 + c15;
                *(unsigned short*)(smem + ck * 32768 + c_out * 256 +
                                   ((2 * mkl) ^ ((c_out & 7) << 4))) = f2bf(vacc[mt][r]);
            }
        }
    }
    __syncthreads();   // B3: Vhat + Khat visible

    // P4 x16: barrier-free key-tile loop. O[16q][128c] per wave, in regs.
    f32x4 o[8];
    #pragma unroll
    for (int ci = 0; ci < 8; ++ci) o[ci] = zacc;
    float lsum = 0.f;

    for (int rep = 0; rep < P4_REPS; ++rep) {
        // reset via *0.0f: keeps the dependency chain live (no DCE of reps),
        // and 0.0f * finite == 0.0f so the final rep's math is bit-identical.
        lsum = lsum * 0.0f;
        #pragma unroll
        for (int ci = 0; ci < 8; ++ci) o[ci] = o[ci] * 0.0f;

        for (int kt = 0; kt < 16; ++kt) {
            int mk0 = kt * 32;
            bf16x8 ka[2];
            #pragma unroll
            for (int ki = 0; ki < 2; ++ki) {
                bf16x8 v = zfrag;
                if (g < 2) v = *(const bf16x8*)(smem + KOFF + (mk0 + ki * 16 + c15) * 32 + g * 16);
                ka[ki] = v;
            }

            f32x4 s0 = MFMA16(ka[0], qf, zacc);
            f32x4 s1 = MFMA16(ka[1], qf, zacc);
            float e00 = __expf(s0[0]), e01 = __expf(s0[1]), e02 = __expf(s0[2]), e03 = __expf(s0[3]);
            float e10 = __expf(s1[0]), e11 = __expf(s1[1]), e12 = __expf(s1[2]), e13 = __expf(s1[3]);
            lsum += (e00 + e01) + (e02 + e03) + ((e10 + e11) + (e12 + e13));
            int wA0 = pkbf(e00, e01), wB0 = pkbf(e02, e03);
            int wA1 = pkbf(e10, e11), wB1 = pkbf(e12, e13);
            int src1 = ((2 * g) & 3) * 16 + c15;
            int src2 = ((2 * g + 1) & 3) * 16 + c15;
            int sA0a = __shfl(wA0, src1, 64), sA1a = __shfl(wA1, src1, 64);
            int sB0a = __shfl(wB0, src1, 64), sB1a = __shfl(wB1, src1, 64);
            int sA0b = __shfl(wA0, src2, 64), sA1b = __shfl(wA1, src2, 64);
            int sB0b = __shfl(wB0, src2, 64), sB1b = __shfl(wB1, src2, 64);
            bool k1 = (g >= 2);
            i32x4 uu = { k1 ? sA1a : sA0a, k1 ? sB1a : sB0a,
                         k1 ? sA1b : sA0b, k1 ? sB1b : sB0b };
            bf16x8 pa = __builtin_bit_cast(bf16x8, uu);

            int ckbase = (mk0 >> 7) * 32768;
            int mklb = (2 * (mk0 & 127)) + 16 * g;
            #pragma unroll
            for (int ci = 0; ci < 8; ++ci) {
                int c = ci * 16 + c15;
                bf16x8 vb = *(const bf16x8*)(smem + ckbase + c * 256 + (mklb ^ ((c & 7) << 4)));
                o[ci] = MFMA16(pa, vb, o[ci]);
            }
        }
    }

    // softmax denominators for this wave's 16 queries
    {
        float l = lsum;
        l += __shfl_xor(l, 16, 64);
        l += __shfl_xor(l, 32, 64);
        if (g == 0)
            *(float*)(smem + LOFF + (wv * 16 + c15) * 4) = l;
    }

    __syncthreads();   // B4: Vhat/Khat reads done, safe to overwrite with O

    #pragma unroll
    for (int ci = 0; ci < 8; ++ci)
        #pragma unroll
        for (int r = 0; r < 4; ++r) {
            int nql = wv * 16 + g * 4 + r;           // 0..127
            int c = ci * 16 + c15;
            *(unsigned short*)(smem + c * 256 + ((2 * nql) ^ ((c & 7) << 4))) = f2bf(o[ci][r]);
        }
    __syncthreads();   // B5: O visible

    // epilogue: in-place RMW on out (out currently holds x from the memcpy)
    float gma = gamma[0];
    int q128 = tid & 127;
    int cb = tid >> 7;
    float invl = 1.0f / *(const float*)(smem + LOFF + q128 * 4);
    int nq = qq * 128 + q128;
    int vox = ((nq >> 6) << 12) + (((nq >> 3) & 7) << 6) + (nq & 7);
    int go = vbase + vox;
    #pragma unroll
    for (int b = 0; b < 4; ++b) {
        float xv[8];
        #pragma unroll
        for (int j = 0; j < 8; ++j) {
            int c = cb * 32 + b * 8 + j;
            xv[j] = out[c * 262144 + go];
        }
        #pragma unroll
        for (int j = 0; j < 8; ++j) {
            int c = cb * 32 + b * 8 + j;
            float ov = bf2f(*(const unsigned short*)(smem + c * 256 + ((2 * q128) ^ ((c & 7) << 4))));
            out[c * 262144 + go] = gma * (ov * invl + bv[c]) + xv[j];
        }
    }
}

extern "C" void kernel_launch(void* const* d_in, const int* in_sizes, int n_in,
                              void* d_out, int out_size, void* d_ws, size_t ws_size,
                              hipStream_t stream) {
    const float* x     = (const float*)d_in[0];
    const float* Wq    = (const float*)d_in[1];
    const float* bq    = (const float*)d_in[2];
    const float* Wk    = (const float*)d_in[3];
    const float* bk    = (const float*)d_in[4];
    const float* Wv    = (const float*)d_in[5];
    const float* bv    = (const float*)d_in[6];
    const float* gamma = (const float*)d_in[7];
    float* out = (float*)d_out;
    (void)in_sizes; (void)n_in; (void)out_size; (void)d_ws; (void)ws_size;

    // 1) SDMA copy: out = x everywhere (diagonal stale, overwritten below).
    hipMemcpyAsync(out, x, (size_t)out_size * sizeof(float),
                   hipMemcpyDeviceToDevice, stream);
    // 2) Diagonal attention with P4 x16 amplification (instrumentation).
    battn_kernel<<<dim3(256), dim3(512), 0, stream>>>(x, Wq, bq, Wk, bk, Wv, bv, gamma, out);
}

// Round 14
// 93.134 us; speedup vs baseline: 2.4146x; 2.4146x over previous
//
#include <hip/hip_runtime.h>

typedef __attribute__((ext_vector_type(8))) short bf16x8;
typedef __attribute__((ext_vector_type(4))) float f32x4;
typedef __attribute__((ext_vector_type(4))) int i32x4;
typedef __attribute__((ext_vector_type(4))) float float4v;

#define MFMA16(a, b, c) __builtin_amdgcn_mfma_f32_16x16x32_bf16((a), (b), (c), 0, 0, 0)

__device__ __forceinline__ unsigned short f2bf(float f) {
    unsigned u = __builtin_bit_cast(unsigned, f);
    u += 0x7fffu + ((u >> 16) & 1u);
    return (unsigned short)(u >> 16);
}
__device__ __forceinline__ float bf2f(unsigned short s) {
    unsigned u = ((unsigned)s) << 16;
    return __builtin_bit_cast(float, u);
}
__device__ __forceinline__ int pkbf(float a, float b) {
    return (int)f2bf(a) | ((int)f2bf(b) << 16);
}

// LDS map (bytes), total 147968 — identical to rounds 12/13.
#define KOFF 131072
#define LOFF 147456

// ---------------------------------------------------------------------------
// Wave-specialized battn: 256 wgs x 1024 threads (16 waves).
//   - staging: ALL 16 waves (2x TLP on the scattered loads)
//   - P1..P4 + O-write: waves 0..7 (byte-identical to round 12)
//   - epilogue: waves 8..15, residuals PREFETCHED right after B3 so the
//     global-read latency hides under P4; after B5 only LDS reads + stores.
// Runs AFTER the SDMA memcpy (out = x everywhere).
// ---------------------------------------------------------------------------
__global__ __launch_bounds__(1024, 1) void battn_kernel(
    const float* __restrict__ x,
    const float* __restrict__ Wq, const float* __restrict__ bq,
    const float* __restrict__ Wk, const float* __restrict__ bk,
    const float* __restrict__ Wv, const float* __restrict__ bv,
    const float* __restrict__ gamma, float* __restrict__ out)
{
    __shared__ __attribute__((aligned(128))) char smem[147968];
    const int tid = threadIdx.x;
    const int bid = blockIdx.x;
    const int p  = ((bid & 7) << 3) | (bid >> 5);   // 64 blocks, 4 wgs/p per XCD
    const int qq = (bid >> 3) & 3;                  // query quarter
    const int ib = p >> 3, jb = p & 7;
    const int vbase = ib * 8 * 4096 + jb * 8 * 64 + ib * 8;
    const int lane = tid & 63, wv = tid >> 6;       // 16 waves
    const int g = lane >> 4, c15 = lane & 15;
    const f32x4 zacc = {0.f, 0.f, 0.f, 0.f};
    const bf16x8 zfrag = (bf16x8)(short)0;

    // phase 0: stage FULL x block -> blk^T bf16 (swizzled). ALL 16 waves.
    #pragma unroll
    for (int b = 0; b < 2; ++b) {
        float4v t[8];
        #pragma unroll
        for (int j = 0; j < 8; ++j) {
            int ch = (b * 8 + j) * 1024 + tid;
            int c = ch >> 7;
            int m = (ch & 127) * 4;
            int vox = ((m >> 6) << 12) + (((m >> 3) & 7) << 6) + (m & 7);
            t[j] = *(const float4v*)(x + c * 262144 + vbase + vox);
        }
        #pragma unroll
        for (int j = 0; j < 8; ++j) {
            int ch = (b * 8 + j) * 1024 + tid;
            int c = ch >> 7;
            int m = (ch & 127) * 4;
            char* bp = smem + ((m * 256 + 2 * c) ^ (((m >> 2) & 7) << 4));
            *(unsigned short*)(bp)       = f2bf(t[j][0]);
            *(unsigned short*)(bp + 256) = f2bf(t[j][1]);
            *(unsigned short*)(bp + 512) = f2bf(t[j][2]);
            *(unsigned short*)(bp + 768) = f2bf(t[j][3]);
        }
    }

    // weight fragments: compute waves only
    bf16x8 wqf[4], wkf[4], wvf[4];
    float bqv = 0.f, bkv = 0.f;
    if (wv < 8) {
        #pragma unroll
        for (int ks = 0; ks < 4; ++ks) {
            const float4v* sq = (const float4v*)(Wq + c15 * 128 + ks * 32 + g * 8);
            const float4v* sk = (const float4v*)(Wk + c15 * 128 + ks * 32 + g * 8);
            const float4v* sv = (const float4v*)(Wv + (wv * 16 + c15) * 128 + ks * 32 + g * 8);
            float4v q0 = sq[0], q1 = sq[1];
            float4v k0 = sk[0], k1 = sk[1];
            float4v v0 = sv[0], v1 = sv[1];
            #pragma unroll
            for (int e = 0; e < 4; ++e) {
                wqf[ks][e] = (short)f2bf(q0[e]); wqf[ks][4 + e] = (short)f2bf(q1[e]);
                wkf[ks][e] = (short)f2bf(k0[e]); wkf[ks][4 + e] = (short)f2bf(k1[e]);
                wvf[ks][e] = (short)f2bf(v0[e]); wvf[ks][4 + e] = (short)f2bf(v1[e]);
            }
        }
        bqv = bq[c15]; bkv = bk[c15];
    }

    __syncthreads();   // B1: blkT staged

    bf16x8 qf = zfrag;
    if (wv < 8) {
        // P1: qhat for this wave's 16 queries (tile qq*128 + wv*16), wave-local
        {
            f32x4 acc = zacc;
            int mrow = qq * 128 + wv * 16 + c15;
            int sw = ((mrow >> 2) & 7) << 4;
            #pragma unroll
            for (int ks = 0; ks < 4; ++ks) {
                bf16x8 af = *(const bf16x8*)(smem + ((mrow * 256 + ks * 64 + g * 16) ^ sw));
                acc = MFMA16(af, wqf[ks], acc);
            }
            #pragma unroll
            for (int r = 0; r < 4; ++r)
                *(unsigned short*)(smem + KOFF + wv * 2048 + (g * 4 + r) * 32 + 2 * c15) = f2bf(acc[r] + bqv);
        }
        if (g < 2) qf = *(const bf16x8*)(smem + KOFF + wv * 2048 + c15 * 32 + g * 16);

        // P2: Khat[mk][d] for this wave's 64 keys (overwrites own scratch slice)
        #pragma unroll
        for (int qi = 0; qi < 4; ++qi) {
            f32x4 acc = zacc;
            int mrow = wv * 64 + qi * 16 + c15;
            int sw = ((mrow >> 2) & 7) << 4;
            #pragma unroll
            for (int ks = 0; ks < 4; ++ks) {
                bf16x8 af = *(const bf16x8*)(smem + ((mrow * 256 + ks * 64 + g * 16) ^ sw));
                acc = MFMA16(af, wkf[ks], acc);
            }
            #pragma unroll
            for (int r = 0; r < 4; ++r) {
                int mk = wv * 64 + qi * 16 + g * 4 + r;
                *(unsigned short*)(smem + KOFF + mk * 32 + 2 * c15) = f2bf(acc[r] + bkv);
            }
        }
    }

    // P3: Vhat in 4 chunks of 128 keys, in-place over consumed blkT rows.
    // Barriers hit by ALL waves; compute/writes by waves 0..7.
    for (int ck = 0; ck < 4; ++ck) {
        f32x4 vacc[8];
        if (wv < 8) {
            #pragma unroll
            for (int mt = 0; mt < 8; ++mt) {
                vacc[mt] = zacc;
                int mrow = ck * 128 + mt * 16 + c15;
                int sw = ((mrow >> 2) & 7) << 4;
                #pragma unroll
                for (int ks = 0; ks < 4; ++ks) {
                    bf16x8 bf = *(const bf16x8*)(smem + ((mrow * 256 + ks * 64 + g * 16) ^ sw));
                    vacc[mt] = MFMA16(wvf[ks], bf, vacc[mt]);
                }
            }
        }
        __syncthreads();
        if (wv < 8) {
            #pragma unroll
            for (int mt = 0; mt < 8; ++mt) {
                #pragma unroll
                for (int r = 0; r < 4; ++r) {
                    int c_out = wv * 16 + g * 4 + r;
                    int mkl = mt * 16 + c15;
                    *(unsigned short*)(smem + ck * 32768 + c_out * 256 +
                                       ((2 * mkl) ^ ((c_out & 7) << 4))) = f2bf(vacc[mt][r]);
                }
            }
        }
    }
    __syncthreads();   // B3: Vhat + Khat visible

    // epilogue prefetch (waves 8..15): issue the 32 residual reads NOW; they
    // complete while waves 0..7 run P4 (we park at B4 with vmcnt drained).
    float xv[32];
    int go_e = 0;
    float invl_dummy;
    (void)invl_dummy;
    if (wv >= 8) {
        int t = tid - 512;
        int q128 = t & 127;
        int cb = t >> 7;                             // 0..3 (32 channels each)
        int nq = qq * 128 + q128;
        int vox = ((nq >> 6) << 12) + (((nq >> 3) & 7) << 6) + (nq & 7);
        go_e = vbase + vox;
        #pragma unroll
        for (int i = 0; i < 32; ++i) {
            int c = cb * 32 + i;
            xv[i] = out[c * 262144 + go_e];          // = x (memcpy'd), hot
        }
    }

    // P4: barrier-free key-tile loop (waves 0..7). O[16q][128c] per wave.
    if (wv < 8) {
        f32x4 o[8];
        #pragma unroll
        for (int ci = 0; ci < 8; ++ci) o[ci] = zacc;
        float lsum = 0.f;

        for (int kt = 0; kt < 16; ++kt) {
            int mk0 = kt * 32;
            bf16x8 ka[2];
            #pragma unroll
            for (int ki = 0; ki < 2; ++ki) {
                bf16x8 v = zfrag;
                if (g < 2) v = *(const bf16x8*)(smem + KOFF + (mk0 + ki * 16 + c15) * 32 + g * 16);
                ka[ki] = v;
            }

            f32x4 s0 = MFMA16(ka[0], qf, zacc);
            f32x4 s1 = MFMA16(ka[1], qf, zacc);
            float e00 = __expf(s0[0]), e01 = __expf(s0[1]), e02 = __expf(s0[2]), e03 = __expf(s0[3]);
            float e10 = __expf(s1[0]), e11 = __expf(s1[1]), e12 = __expf(s1[2]), e13 = __expf(s1[3]);
            lsum += (e00 + e01) + (e02 + e03) + ((e10 + e11) + (e12 + e13));
            int wA0 = pkbf(e00, e01), wB0 = pkbf(e02, e03);
            int wA1 = pkbf(e10, e11), wB1 = pkbf(e12, e13);
            int src1 = ((2 * g) & 3) * 16 + c15;
            int src2 = ((2 * g + 1) & 3) * 16 + c15;
            int sA0a = __shfl(wA0, src1, 64), sA1a = __shfl(wA1, src1, 64);
            int sB0a = __shfl(wB0, src1, 64), sB1a = __shfl(wB1, src1, 64);
            int sA0b = __shfl(wA0, src2, 64), sA1b = __shfl(wA1, src2, 64);
            int sB0b = __shfl(wB0, src2, 64), sB1b = __shfl(wB1, src2, 64);
            bool k1 = (g >= 2);
            i32x4 uu = { k1 ? sA1a : sA0a, k1 ? sB1a : sB0a,
                         k1 ? sA1b : sA0b, k1 ? sB1b : sB0b };
            bf16x8 pa = __builtin_bit_cast(bf16x8, uu);

            int ckbase = (mk0 >> 7) * 32768;
            int mklb = (2 * (mk0 & 127)) + 16 * g;
            #pragma unroll
            for (int ci = 0; ci < 8; ++ci) {
                int c = ci * 16 + c15;
                bf16x8 vb = *(const bf16x8*)(smem + ckbase + c * 256 + (mklb ^ ((c & 7) << 4)));
                o[ci] = MFMA16(pa, vb, o[ci]);
            }
        }

        // softmax denominators for this wave's 16 queries
        {
            float l = lsum;
            l += __shfl_xor(l, 16, 64);
            l += __shfl_xor(l, 32, 64);
            if (g == 0)
                *(float*)(smem + LOFF + (wv * 16 + c15) * 4) = l;
        }

        __syncthreads();   // B4

        #pragma unroll
        for (int ci = 0; ci < 8; ++ci)
            #pragma unroll
            for (int r = 0; r < 4; ++r) {
                int nql = wv * 16 + g * 4 + r;       // 0..127
                int c = ci * 16 + c15;
                *(unsigned short*)(smem + c * 256 + ((2 * nql) ^ ((c & 7) << 4))) = f2bf(o[ci][r]);
            }
        __syncthreads();   // B5
    } else {
        __syncthreads();   // B4
        __syncthreads();   // B5
    }

    // epilogue (waves 8..15): out = gamma*(O/l + bv) + x, x prefetched.
    if (wv >= 8) {
        float gma = gamma[0];
        int t = tid - 512;
        int q128 = t & 127;
        int cb = t >> 7;
        float invl = 1.0f / *(const float*)(smem + LOFF + q128 * 4);
        #pragma unroll
        for (int i = 0; i < 32; ++i) {
            int c = cb * 32 + i;
            float ov = bf2f(*(const unsigned short*)(smem + c * 256 + ((2 * q128) ^ ((c & 7) << 4))));
            out[c * 262144 + go_e] = gma * (ov * invl + bv[c]) + xv[i];
        }
    }
}

extern "C" void kernel_launch(void* const* d_in, const int* in_sizes, int n_in,
                              void* d_out, int out_size, void* d_ws, size_t ws_size,
                              hipStream_t stream) {
    const float* x     = (const float*)d_in[0];
    const float* Wq    = (const float*)d_in[1];
    const float* bq    = (const float*)d_in[2];
    const float* Wk    = (const float*)d_in[3];
    const float* bk    = (const float*)d_in[4];
    const float* Wv    = (const float*)d_in[5];
    const float* bv    = (const float*)d_in[6];
    const float* gamma = (const float*)d_in[7];
    float* out = (float*)d_out;
    (void)in_sizes; (void)n_in; (void)out_size; (void)d_ws; (void)ws_size;

    // 1) SDMA copy: out = x everywhere (diagonal stale, overwritten below).
    hipMemcpyAsync(out, x, (size_t)out_size * sizeof(float),
                   hipMemcpyDeviceToDevice, stream);
    // 2) Wave-specialized diagonal attention (1024 thr: 16-wave staging,
    //    8-wave compute, 8-wave prefetched epilogue).
    battn_kernel<<<dim3(256), dim3(1024), 0, stream>>>(x, Wq, bq, Wk, bk, Wv, bv, gamma, out);
}